// Round 1
// baseline (659.426 us; speedup 1.0000x reference)
//
#include <hip/hip_runtime.h>

typedef __bf16 bf16;
typedef __bf16 bf16x4 __attribute__((ext_vector_type(4)));
typedef __bf16 bf16x8 __attribute__((ext_vector_type(8)));
typedef float  f32x4  __attribute__((ext_vector_type(4)));

constexpr int NB  = 16;    // batch
constexpr int IDF = 1024;
constexpr int CDF = 256;
constexpr int L   = 256;
constexpr int M   = 4096;  // ih*iw

// ---------------- prep: w2 f32 -> bf16 ----------------
__global__ __launch_bounds__(256) void k_prep_w2(const float* __restrict__ w2,
                                                 bf16* __restrict__ w2b) {
    int i = (blockIdx.x * 256 + threadIdx.x) * 4;
    float4 v = *reinterpret_cast<const float4*>(w2 + i);
    bf16x4 o; o[0] = (bf16)v.x; o[1] = (bf16)v.y; o[2] = (bf16)v.z; o[3] = (bf16)v.w;
    *reinterpret_cast<bf16x4*>(w2b + i) = o;
}

// ---------------- prep: context [b][c][l] f32 -> ctxT [b][l][c] bf16 ----------------
__global__ __launch_bounds__(256) void k_prep_ctxT(const float* __restrict__ ctx,
                                                   bf16* __restrict__ ctxT) {
    __shared__ float tb[32][33];
    int b = blockIdx.z, c0 = blockIdx.y * 32, l0 = blockIdx.x * 32;
    int tx = threadIdx.x, ty = threadIdx.y;   // 32 x 8
    const float* src = ctx + (size_t)b * CDF * L;
#pragma unroll
    for (int j = 0; j < 4; j++) tb[ty + 8*j][tx] = src[(size_t)(c0 + ty + 8*j) * L + l0 + tx];
    __syncthreads();
    bf16* dst = ctxT + (size_t)b * L * CDF;
#pragma unroll
    for (int j = 0; j < 4; j++) dst[(size_t)(l0 + ty + 8*j) * CDF + c0 + tx] = (bf16)tb[tx][ty + 8*j];
}

// ---------------- GEMM1: sourceC[m,l] = sum_c w2[m,c]*ctx[c,l]  (K=256) ----------------
// writes SC = [b][m][l] bf16  and  ST = [b][l][m] bf16 (LDS transpose)
__global__ __launch_bounds__(256) void k_gemm1(const bf16* __restrict__ w2b,
                                               const bf16* __restrict__ ctxT,
                                               bf16* __restrict__ SC,
                                               bf16* __restrict__ ST) {
    __shared__ alignas(16) char smem[2 * 128 * 72 * 2];            // 36864 B
    bf16 (*As)[72]  = reinterpret_cast<bf16(*)[72]>(smem);
    bf16 (*Bs)[72]  = reinterpret_cast<bf16(*)[72]>(smem + 128 * 72 * 2);
    bf16 (*Cs)[136] = reinterpret_cast<bf16(*)[136]>(smem);        // epilogue alias (34816 B)

    const int b  = blockIdx.z;
    const int m0 = blockIdx.y * 128;
    const int l0 = blockIdx.x * 128;
    const int t = threadIdx.x;
    const int lane = t & 63, wid = t >> 6;
    const int wr = (wid >> 1) * 64, wc = (wid & 1) * 64;

    const bf16* Ag = w2b + (size_t)m0 * CDF;
    const bf16* Bg = ctxT + (size_t)b * L * CDF + (size_t)l0 * CDF;

    f32x4 acc[4][4] = {};
    for (int k0 = 0; k0 < CDF; k0 += 64) {
#pragma unroll
        for (int j = 0; j < 4; j++) {
            int idx = (j * 256 + t) * 8; int r = idx >> 6, c = idx & 63;
            *reinterpret_cast<bf16x8*>(&As[r][c]) =
                *reinterpret_cast<const bf16x8*>(&Ag[(size_t)r * CDF + k0 + c]);
        }
#pragma unroll
        for (int j = 0; j < 4; j++) {
            int idx = (j * 256 + t) * 8; int r = idx >> 6, c = idx & 63;
            *reinterpret_cast<bf16x8*>(&Bs[r][c]) =
                *reinterpret_cast<const bf16x8*>(&Bg[(size_t)r * CDF + k0 + c]);
        }
        __syncthreads();
#pragma unroll
        for (int kk = 0; kk < 2; kk++) {
            const int kb = kk * 32 + (lane >> 4) * 8;
            bf16x8 af[4], bb[4];
#pragma unroll
            for (int f = 0; f < 4; f++)
                af[f] = *reinterpret_cast<const bf16x8*>(&As[wr + f * 16 + (lane & 15)][kb]);
#pragma unroll
            for (int f = 0; f < 4; f++)
                bb[f] = *reinterpret_cast<const bf16x8*>(&Bs[wc + f * 16 + (lane & 15)][kb]);
#pragma unroll
            for (int fm = 0; fm < 4; fm++)
#pragma unroll
                for (int fn = 0; fn < 4; fn++)
                    acc[fm][fn] = __builtin_amdgcn_mfma_f32_16x16x32_bf16(af[fm], bb[fn], acc[fm][fn], 0, 0, 0);
        }
        __syncthreads();
    }
    // epilogue: acc -> Cs (bf16)
#pragma unroll
    for (int fm = 0; fm < 4; fm++)
#pragma unroll
        for (int fn = 0; fn < 4; fn++) {
            int row = wr + fm * 16 + ((lane >> 4) << 2);
            int col = wc + fn * 16 + (lane & 15);
#pragma unroll
            for (int r = 0; r < 4; r++) Cs[row + r][col] = (bf16)acc[fm][fn][r];
        }
    __syncthreads();
    // SC: natural [m][l], vectorized
    bf16* sc = SC + (size_t)b * M * L + (size_t)m0 * L + l0;
#pragma unroll
    for (int j = 0; j < 8; j++) {
        int idx = (j * 256 + t) * 8; int r = idx >> 7, c = idx & 127;
        *reinterpret_cast<bf16x8*>(&sc[(size_t)r * L + c]) =
            *reinterpret_cast<const bf16x8*>(&Cs[r][c]);
    }
    // ST: transposed [l][m], gather columns from LDS
    bf16* st = ST + (size_t)b * L * M + (size_t)l0 * M + m0;
#pragma unroll
    for (int j = 0; j < 8; j++) {
        int idx = (j * 256 + t) * 8; int lr = idx >> 7, c = idx & 127;
        bf16x8 v;
#pragma unroll
        for (int u = 0; u < 8; u++) v[u] = Cs[c + u][lr];
        *reinterpret_cast<bf16x8*>(&st[(size_t)lr * M + c]) = v;
    }
}

// ---------------- GEMM2 + softmax: attn[i,l] = softmax_l( sum_m WC[i,m]*SC[m,l] ) ----------------
// A = WC f32 (convert in staging), B = ST [l][m] bf16. BM=32, BN=256(=L), BK=64.
// writes AT = attn bf16 [b][i][l]  and  attn_c f32 [b][l][i] (output 1)
__global__ __launch_bounds__(256) void k_attn(const float* __restrict__ WC,
                                              const bf16* __restrict__ ST,
                                              bf16* __restrict__ AT,
                                              float* __restrict__ attn_c) {
    __shared__ alignas(16) char smem[32 * 72 * 2 + 256 * 72 * 2];  // 41472 B
    bf16 (*As)[72] = reinterpret_cast<bf16(*)[72]>(smem);
    bf16 (*Bs)[72] = reinterpret_cast<bf16(*)[72]>(smem + 32 * 72 * 2);
    float (*Lg)[257] = reinterpret_cast<float(*)[257]>(smem);      // 32896 B alias (post K-loop)
    __shared__ float red[32][9];
    __shared__ float invbuf[32];

    const int b  = blockIdx.y;
    const int i0 = blockIdx.x * 32;
    const int t = threadIdx.x;
    const int lane = t & 63, w = t >> 6;

    const float* Ag = WC + (size_t)b * IDF * M + (size_t)i0 * M;
    const bf16*  Bg = ST + (size_t)b * L * M;

    f32x4 acc[2][4] = {};
    for (int k0 = 0; k0 < M; k0 += 64) {
#pragma unroll
        for (int j = 0; j < 2; j++) {          // A: 32x64 f32 -> bf16
            int idx = (j * 256 + t) * 4; int r = idx >> 6, c = idx & 63;
            float4 v = *reinterpret_cast<const float4*>(&Ag[(size_t)r * M + k0 + c]);
            bf16x4 o; o[0] = (bf16)v.x; o[1] = (bf16)v.y; o[2] = (bf16)v.z; o[3] = (bf16)v.w;
            *reinterpret_cast<bf16x4*>(&As[r][c]) = o;
        }
#pragma unroll
        for (int j = 0; j < 8; j++) {          // B: 256x64 bf16
            int idx = (j * 256 + t) * 8; int r = idx >> 6, c = idx & 63;
            *reinterpret_cast<bf16x8*>(&Bs[r][c]) =
                *reinterpret_cast<const bf16x8*>(&Bg[(size_t)r * M + k0 + c]);
        }
        __syncthreads();
#pragma unroll
        for (int kk = 0; kk < 2; kk++) {
            const int kb = kk * 32 + (lane >> 4) * 8;
            bf16x8 af[2], bb[4];
#pragma unroll
            for (int f = 0; f < 2; f++)
                af[f] = *reinterpret_cast<const bf16x8*>(&As[f * 16 + (lane & 15)][kb]);
#pragma unroll
            for (int f = 0; f < 4; f++)
                bb[f] = *reinterpret_cast<const bf16x8*>(&Bs[w * 64 + f * 16 + (lane & 15)][kb]);
#pragma unroll
            for (int fm = 0; fm < 2; fm++)
#pragma unroll
                for (int fn = 0; fn < 4; fn++)
                    acc[fm][fn] = __builtin_amdgcn_mfma_f32_16x16x32_bf16(af[fm], bb[fn], acc[fm][fn], 0, 0, 0);
        }
        __syncthreads();
    }
    // logits -> Lg (aliases staging LDS; all reads drained by final barrier above)
#pragma unroll
    for (int fm = 0; fm < 2; fm++)
#pragma unroll
        for (int fn = 0; fn < 4; fn++) {
            int row = fm * 16 + ((lane >> 4) << 2);
            int col = w * 64 + fn * 16 + (lane & 15);
#pragma unroll
            for (int r = 0; r < 4; r++) Lg[row + r][col] = acc[fm][fn][r];
        }
    __syncthreads();
    // row softmax: thread (srow, sseg) owns 32 contiguous cols
    const int srow = t & 31, sseg = t >> 5;
    float mx = -3.0e38f;
    for (int j = 0; j < 32; j++) mx = fmaxf(mx, Lg[srow][sseg * 32 + j]);
    red[srow][sseg] = mx;
    __syncthreads();
    float mrow = red[srow][0];
#pragma unroll
    for (int s = 1; s < 8; s++) mrow = fmaxf(mrow, red[srow][s]);
    __syncthreads();                            // all max reads done before red reuse
    float ps = 0.f;
    for (int j = 0; j < 32; j++) {
        float e = __expf(Lg[srow][sseg * 32 + j] - mrow);
        Lg[srow][sseg * 32 + j] = e;
        ps += e;
    }
    red[srow][sseg] = ps;
    __syncthreads();
    float sum = 0.f;
#pragma unroll
    for (int s = 0; s < 8; s++) sum += red[srow][s];
    const float inv = 1.0f / sum;
    if (sseg == 0) invbuf[srow] = inv;
    __syncthreads();
    // attn bf16 [b][i0+srow][l]
    bf16* at = AT + (size_t)b * IDF * L + (size_t)i0 * L;
#pragma unroll
    for (int u = 0; u < 4; u++) {
        bf16x8 v;
#pragma unroll
        for (int q = 0; q < 8; q++) v[q] = (bf16)(Lg[srow][sseg * 32 + u * 8 + q] * inv);
        *reinterpret_cast<bf16x8*>(&at[(size_t)srow * L + sseg * 32 + u * 8]) = v;
    }
    // attn_c f32 [b][l][i0+i], coalesced over i
    float* ac = attn_c + (size_t)b * L * IDF + i0;
    const int i = t & 31, ls = t >> 5;
    const float invi = invbuf[i];
    for (int l = ls; l < L; l += 8)
        ac[(size_t)l * IDF + i] = Lg[i][l] * invi;
}

// ---------------- GEMM3: out[b][i][m] = sum_l attn[i,l]*SC[m,l]  (K=256) ----------------
__global__ __launch_bounds__(256) void k_gemm3(const bf16* __restrict__ AT,
                                               const bf16* __restrict__ SC,
                                               float* __restrict__ out0) {
    __shared__ alignas(16) bf16 As[128][72];
    __shared__ alignas(16) bf16 Bs[128][72];
    const int b  = blockIdx.z;
    const int i0 = blockIdx.y * 128;
    const int m0 = blockIdx.x * 128;
    const int t = threadIdx.x;
    const int lane = t & 63, wid = t >> 6;
    const int wr = (wid >> 1) * 64, wc = (wid & 1) * 64;
    const bf16* Ag = AT + (size_t)b * IDF * L + (size_t)i0 * L;
    const bf16* Bg = SC + (size_t)b * M * L + (size_t)m0 * L;
    f32x4 acc[4][4] = {};
    for (int k0 = 0; k0 < L; k0 += 64) {
#pragma unroll
        for (int j = 0; j < 4; j++) {
            int idx = (j * 256 + t) * 8; int r = idx >> 6, c = idx & 63;
            *reinterpret_cast<bf16x8*>(&As[r][c]) =
                *reinterpret_cast<const bf16x8*>(&Ag[(size_t)r * L + k0 + c]);
        }
#pragma unroll
        for (int j = 0; j < 4; j++) {
            int idx = (j * 256 + t) * 8; int r = idx >> 6, c = idx & 63;
            *reinterpret_cast<bf16x8*>(&Bs[r][c]) =
                *reinterpret_cast<const bf16x8*>(&Bg[(size_t)r * L + k0 + c]);
        }
        __syncthreads();
#pragma unroll
        for (int kk = 0; kk < 2; kk++) {
            const int kb = kk * 32 + (lane >> 4) * 8;
            bf16x8 af[4], bb[4];
#pragma unroll
            for (int f = 0; f < 4; f++)
                af[f] = *reinterpret_cast<const bf16x8*>(&As[wr + f * 16 + (lane & 15)][kb]);
#pragma unroll
            for (int f = 0; f < 4; f++)
                bb[f] = *reinterpret_cast<const bf16x8*>(&Bs[wc + f * 16 + (lane & 15)][kb]);
#pragma unroll
            for (int fm = 0; fm < 4; fm++)
#pragma unroll
                for (int fn = 0; fn < 4; fn++)
                    acc[fm][fn] = __builtin_amdgcn_mfma_f32_16x16x32_bf16(af[fm], bb[fn], acc[fm][fn], 0, 0, 0);
        }
        __syncthreads();
    }
    float* o = out0 + (size_t)b * IDF * M + (size_t)(i0 + wr) * M + m0 + wc;
#pragma unroll
    for (int fm = 0; fm < 4; fm++)
#pragma unroll
        for (int fn = 0; fn < 4; fn++) {
            int row = fm * 16 + ((lane >> 4) << 2);
            int col = fn * 16 + (lane & 15);
#pragma unroll
            for (int r = 0; r < 4; r++) o[(size_t)(row + r) * M + col] = acc[fm][fn][r];
        }
}

extern "C" void kernel_launch(void* const* d_in, const int* in_sizes, int n_in,
                              void* d_out, int out_size, void* d_ws, size_t ws_size,
                              hipStream_t stream) {
    const float* WC  = (const float*)d_in[0];   // [16,1024,4096]
    const float* ctx = (const float*)d_in[1];   // [16,256,256]
    const float* w2  = (const float*)d_in[2];   // [4096,256]
    float* out0 = (float*)d_out;                           // [16,1024,4096]
    float* out1 = out0 + (size_t)NB * IDF * M;             // [16,256,1024]

    // workspace: SC (32MB) + AT (8MB) + w2 bf16 (2MB) + ctxT bf16 (2MB) = ~46MB
    bf16* SCp  = (bf16*)d_ws;                       // [16][4096][256]
    bf16* ATp  = SCp + (size_t)NB * M * L;          // [16][1024][256]
    bf16* W2B  = ATp + (size_t)NB * IDF * L;        // [4096][256]
    bf16* CTXT = W2B + (size_t)M * CDF;             // [16][256][256]
    // ST = sourceC^T [16][256][4096] bf16 (32MB) lives in out0's region:
    // fully written by k_gemm1, consumed by k_attn, then out0 overwritten by k_gemm3.
    bf16* STp  = (bf16*)d_out;

    k_prep_w2 <<<dim3(M * CDF / 1024), 256, 0, stream>>>(w2, W2B);
    k_prep_ctxT<<<dim3(L / 32, CDF / 32, NB), dim3(32, 8), 0, stream>>>(ctx, CTXT);
    k_gemm1  <<<dim3(L / 128, M / 128, NB), 256, 0, stream>>>(W2B, CTXT, SCp, STp);
    k_attn   <<<dim3(IDF / 32, NB), 256, 0, stream>>>(WC, STp, ATp, out1);
    k_gemm3  <<<dim3(M / 128, IDF / 128, NB), 256, 0, stream>>>(ATp, SCp, out0);
}

// Round 2
// 609.003 us; speedup vs baseline: 1.0828x; 1.0828x over previous
//
#include <hip/hip_runtime.h>

typedef __bf16 bf16;
typedef __bf16 bf16x4 __attribute__((ext_vector_type(4)));
typedef __bf16 bf16x8 __attribute__((ext_vector_type(8)));
typedef float  f32x4  __attribute__((ext_vector_type(4)));

constexpr int NB  = 16;    // batch
constexpr int IDF = 1024;
constexpr int CDF = 256;
constexpr int L   = 256;
constexpr int M   = 4096;  // ih*iw

// async global->LDS, 16B per lane. LDS dest is wave-uniform base + lane*16.
__device__ __forceinline__ void gl_lds16(const void* g, void* l) {
    __builtin_amdgcn_global_load_lds(
        (const __attribute__((address_space(1))) unsigned int*)g,
        (__attribute__((address_space(3))) unsigned int*)l, 16, 0, 0);
}

// ---------------- prep: w2 f32 -> bf16 ----------------
__global__ __launch_bounds__(256) void k_prep_w2(const float* __restrict__ w2,
                                                 bf16* __restrict__ w2b) {
    int i = (blockIdx.x * 256 + threadIdx.x) * 4;
    float4 v = *reinterpret_cast<const float4*>(w2 + i);
    bf16x4 o; o[0] = (bf16)v.x; o[1] = (bf16)v.y; o[2] = (bf16)v.z; o[3] = (bf16)v.w;
    *reinterpret_cast<bf16x4*>(w2b + i) = o;
}

// ---------------- prep: context [b][c][l] f32 -> ctxT [b][l][c] bf16 ----------------
__global__ __launch_bounds__(256) void k_prep_ctxT(const float* __restrict__ ctx,
                                                   bf16* __restrict__ ctxT) {
    __shared__ float tb[32][33];
    int b = blockIdx.z, c0 = blockIdx.y * 32, l0 = blockIdx.x * 32;
    int tx = threadIdx.x, ty = threadIdx.y;   // 32 x 8
    const float* src = ctx + (size_t)b * CDF * L;
#pragma unroll
    for (int j = 0; j < 4; j++) tb[ty + 8*j][tx] = src[(size_t)(c0 + ty + 8*j) * L + l0 + tx];
    __syncthreads();
    bf16* dst = ctxT + (size_t)b * L * CDF;
#pragma unroll
    for (int j = 0; j < 4; j++) dst[(size_t)(l0 + ty + 8*j) * CDF + c0 + tx] = (bf16)tb[tx][ty + 8*j];
}

// ---------------- GEMM1: sourceC[m,l] = sum_c w2[m,c]*ctx[c,l]  (K=256) ----------------
__global__ __launch_bounds__(256) void k_gemm1(const bf16* __restrict__ w2b,
                                               const bf16* __restrict__ ctxT,
                                               bf16* __restrict__ SC,
                                               bf16* __restrict__ ST) {
    __shared__ alignas(16) char smem[2 * 128 * 72 * 2];            // 36864 B
    bf16 (*As)[72]  = reinterpret_cast<bf16(*)[72]>(smem);
    bf16 (*Bs)[72]  = reinterpret_cast<bf16(*)[72]>(smem + 128 * 72 * 2);
    bf16 (*Cs)[136] = reinterpret_cast<bf16(*)[136]>(smem);        // epilogue alias (34816 B)

    const int b  = blockIdx.z;
    const int m0 = blockIdx.y * 128;
    const int l0 = blockIdx.x * 128;
    const int t = threadIdx.x;
    const int lane = t & 63, wid = t >> 6;
    const int wr = (wid >> 1) * 64, wc = (wid & 1) * 64;

    const bf16* Ag = w2b + (size_t)m0 * CDF;
    const bf16* Bg = ctxT + (size_t)b * L * CDF + (size_t)l0 * CDF;

    f32x4 acc[4][4] = {};
    for (int k0 = 0; k0 < CDF; k0 += 64) {
#pragma unroll
        for (int j = 0; j < 4; j++) {
            int idx = (j * 256 + t) * 8; int r = idx >> 6, c = idx & 63;
            *reinterpret_cast<bf16x8*>(&As[r][c]) =
                *reinterpret_cast<const bf16x8*>(&Ag[(size_t)r * CDF + k0 + c]);
        }
#pragma unroll
        for (int j = 0; j < 4; j++) {
            int idx = (j * 256 + t) * 8; int r = idx >> 6, c = idx & 63;
            *reinterpret_cast<bf16x8*>(&Bs[r][c]) =
                *reinterpret_cast<const bf16x8*>(&Bg[(size_t)r * CDF + k0 + c]);
        }
        __syncthreads();
#pragma unroll
        for (int kk = 0; kk < 2; kk++) {
            const int kb = kk * 32 + (lane >> 4) * 8;
            bf16x8 af[4], bb[4];
#pragma unroll
            for (int f = 0; f < 4; f++)
                af[f] = *reinterpret_cast<const bf16x8*>(&As[wr + f * 16 + (lane & 15)][kb]);
#pragma unroll
            for (int f = 0; f < 4; f++)
                bb[f] = *reinterpret_cast<const bf16x8*>(&Bs[wc + f * 16 + (lane & 15)][kb]);
#pragma unroll
            for (int fm = 0; fm < 4; fm++)
#pragma unroll
                for (int fn = 0; fn < 4; fn++)
                    acc[fm][fn] = __builtin_amdgcn_mfma_f32_16x16x32_bf16(af[fm], bb[fn], acc[fm][fn], 0, 0, 0);
        }
        __syncthreads();
    }
    // epilogue: acc -> Cs (bf16)
#pragma unroll
    for (int fm = 0; fm < 4; fm++)
#pragma unroll
        for (int fn = 0; fn < 4; fn++) {
            int row = wr + fm * 16 + ((lane >> 4) << 2);
            int col = wc + fn * 16 + (lane & 15);
#pragma unroll
            for (int r = 0; r < 4; r++) Cs[row + r][col] = (bf16)acc[fm][fn][r];
        }
    __syncthreads();
    // SC: natural [m][l], vectorized
    bf16* sc = SC + (size_t)b * M * L + (size_t)m0 * L + l0;
#pragma unroll
    for (int j = 0; j < 8; j++) {
        int idx = (j * 256 + t) * 8; int r = idx >> 7, c = idx & 127;
        *reinterpret_cast<bf16x8*>(&sc[(size_t)r * L + c]) =
            *reinterpret_cast<const bf16x8*>(&Cs[r][c]);
    }
    // ST: transposed [l][m], gather columns from LDS
    bf16* st = ST + (size_t)b * L * M + (size_t)l0 * M + m0;
#pragma unroll
    for (int j = 0; j < 8; j++) {
        int idx = (j * 256 + t) * 8; int lr = idx >> 7, c = idx & 127;
        bf16x8 v;
#pragma unroll
        for (int u = 0; u < 8; u++) v[u] = Cs[c + u][lr];
        *reinterpret_cast<bf16x8*>(&st[(size_t)lr * M + c]) = v;
    }
}

// ---------------- GEMM2 + softmax (fused): attn[i,l] = softmax_l( WC[i,:] . ST[l,:] ) ----------------
// BM=64 rows of idf, BN=256(=L), BK=64. 512 threads, 8 waves (2 M x 4 N), 256 blocks.
// B staged via global_load_lds with both-sides XOR swizzle; A f32->bf16 manual stage, same swizzle.
// Softmax entirely in registers (shfl over 16-lane col groups + small LDS cross-wave reduce).
__global__ __launch_bounds__(512) void k_attn(const float* __restrict__ WC,
                                              const bf16* __restrict__ ST,
                                              bf16* __restrict__ AT,
                                              float* __restrict__ attn_c) {
    __shared__ alignas(16) char smem[64 * 64 * 2 + 256 * 64 * 2];  // As 8KB + Bs 32KB
    bf16* As = reinterpret_cast<bf16*>(smem);                      // [64][64] swizzled
    bf16* Bs = reinterpret_cast<bf16*>(smem + 8192);               // [256][64] swizzled
    float (*Pl)[68] = reinterpret_cast<float(*)[68]>(smem);        // [128][68] f32 bounce (34816B alias)
    __shared__ float redm[64][4];
    __shared__ float reds[64][4];

    const int b  = blockIdx.y;
    const int i0 = blockIdx.x * 64;
    const int t = threadIdx.x, lane = t & 63, wid = t >> 6;
    const int wm = (wid >> 2) * 32, wn = (wid & 3) * 64;

    const float* Ag = WC + (size_t)b * IDF * M + (size_t)i0 * M;
    const bf16*  Bg = ST + (size_t)b * L * M;

    const int arow = t >> 3;                       // 0..63
    const int acol = (t & 7) * 8;                  // global col chunk
    const int aswz = (((t & 7) ^ (arow & 7)) * 8); // swizzled LDS chunk (elems)
    const int brow_in = lane >> 3;                 // 0..7 within an 8-row group
    const int bsrc = (((lane & 7) ^ brow_in) * 8); // inverse-swizzled global chunk (elems)

    f32x4 acc[2][4] = {};
    for (int k0 = 0; k0 < M; k0 += 64) {
        // A: 64x64 f32 -> bf16, swizzled ds_write_b128
        float4 v0 = *reinterpret_cast<const float4*>(&Ag[(size_t)arow * M + k0 + acol]);
        float4 v1 = *reinterpret_cast<const float4*>(&Ag[(size_t)arow * M + k0 + acol + 4]);
        bf16x8 av;
        av[0] = (bf16)v0.x; av[1] = (bf16)v0.y; av[2] = (bf16)v0.z; av[3] = (bf16)v0.w;
        av[4] = (bf16)v1.x; av[5] = (bf16)v1.y; av[6] = (bf16)v1.z; av[7] = (bf16)v1.w;
        *reinterpret_cast<bf16x8*>(&As[arow * 64 + aswz]) = av;
        // B: 256x64 bf16 via global_load_lds, 4 calls/wave, rows q*8..q*8+7 per call
#pragma unroll
        for (int j = 0; j < 4; j++) {
            int q = wid * 4 + j;                   // 0..31
            int row = q * 8 + brow_in;
            gl_lds16(&Bg[(size_t)row * M + k0 + bsrc], &Bs[q * 512]);
        }
        __syncthreads();
#pragma unroll
        for (int kk = 0; kk < 2; kk++) {
            const int g = kk * 4 + (lane >> 4);
            bf16x8 af[2], bb[4];
#pragma unroll
            for (int f = 0; f < 2; f++) {
                int row = wm + f * 16 + (lane & 15);
                af[f] = *reinterpret_cast<const bf16x8*>(&As[row * 64 + ((g ^ (row & 7)) * 8)]);
            }
#pragma unroll
            for (int f = 0; f < 4; f++) {
                int row = wn + f * 16 + (lane & 15);
                bb[f] = *reinterpret_cast<const bf16x8*>(&Bs[row * 64 + ((g ^ (row & 7)) * 8)]);
            }
#pragma unroll
            for (int fm = 0; fm < 2; fm++)
#pragma unroll
                for (int fn = 0; fn < 4; fn++)
                    acc[fm][fn] = __builtin_amdgcn_mfma_f32_16x16x32_bf16(af[fm], bb[fn], acc[fm][fn], 0, 0, 0);
        }
        __syncthreads();
    }

    // ---- softmax in registers: rows = wm + fm*16 + (lane>>4)*4 + r; cols = wn + fn*16 + (lane&15)
    // row max
#pragma unroll
    for (int fm = 0; fm < 2; fm++)
#pragma unroll
        for (int r = 0; r < 4; r++) {
            float mx = fmaxf(fmaxf(acc[fm][0][r], acc[fm][1][r]),
                             fmaxf(acc[fm][2][r], acc[fm][3][r]));
#pragma unroll
            for (int sh = 1; sh < 16; sh <<= 1) mx = fmaxf(mx, __shfl_xor(mx, sh));
            if ((lane & 15) == 0)
                redm[wm + fm * 16 + (lane >> 4) * 4 + r][wid & 3] = mx;
        }
    __syncthreads();
    // exp + row sum
#pragma unroll
    for (int fm = 0; fm < 2; fm++)
#pragma unroll
        for (int r = 0; r < 4; r++) {
            int row = wm + fm * 16 + (lane >> 4) * 4 + r;
            float mr = fmaxf(fmaxf(redm[row][0], redm[row][1]),
                             fmaxf(redm[row][2], redm[row][3]));
            float s = 0.f;
#pragma unroll
            for (int fn = 0; fn < 4; fn++) {
                float e = __expf(acc[fm][fn][r] - mr);
                acc[fm][fn][r] = e;
                s += e;
            }
#pragma unroll
            for (int sh = 1; sh < 16; sh <<= 1) s += __shfl_xor(s, sh);
            if ((lane & 15) == 0) reds[row][wid & 3] = s;
        }
    __syncthreads();
    float inv_[2][4];
#pragma unroll
    for (int fm = 0; fm < 2; fm++)
#pragma unroll
        for (int r = 0; r < 4; r++) {
            int row = wm + fm * 16 + (lane >> 4) * 4 + r;
            inv_[fm][r] = 1.0f / (reds[row][0] + reds[row][1] + reds[row][2] + reds[row][3]);
        }

    // AT bf16 [b][i][l] direct from regs (16-lane = 32B segments)
    bf16* at = AT + (size_t)b * IDF * L + (size_t)i0 * L;
#pragma unroll
    for (int fm = 0; fm < 2; fm++)
#pragma unroll
        for (int r = 0; r < 4; r++) {
            int row = wm + fm * 16 + (lane >> 4) * 4 + r;
#pragma unroll
            for (int fn = 0; fn < 4; fn++) {
                int col = wn + fn * 16 + (lane & 15);
                at[(size_t)row * L + col] = (bf16)(acc[fm][fn][r] * inv_[fm][r]);
            }
        }

    // attn_c f32 [b][l][i0+i] via LDS bounce, 2 chunks of 128 l-cols
    float* ac = attn_c + (size_t)b * L * IDF + i0;
#pragma unroll
    for (int c = 0; c < 2; c++) {
        __syncthreads();                 // Pl free (staging reads / prev chunk reads done)
        if (((wid & 3) >> 1) == c) {
#pragma unroll
            for (int fm = 0; fm < 2; fm++)
#pragma unroll
                for (int r = 0; r < 4; r++) {
                    int row = wm + fm * 16 + (lane >> 4) * 4 + r;
                    float iv = inv_[fm][r];
#pragma unroll
                    for (int fn = 0; fn < 4; fn++) {
                        int col = wn + fn * 16 + (lane & 15) - c * 128;
                        Pl[col][row] = acc[fm][fn][r] * iv;
                    }
                }
        }
        __syncthreads();
#pragma unroll
        for (int s = 0; s < 4; s++) {
            int lr = (t >> 4) + s * 32;          // 0..127
            int fl = (t & 15) * 4;               // f32 idx within 64-wide i
            *reinterpret_cast<float4*>(&ac[(size_t)(c * 128 + lr) * IDF + fl]) =
                *reinterpret_cast<const float4*>(&Pl[lr][fl]);
        }
    }
}

// ---------------- GEMM3: out[b][i][m] = sum_l attn[i,l]*SC[m,l]  (K=256) ----------------
// m97 structure: 128x128 tile, global_load_lds staging with both-sides swizzle.
__global__ __launch_bounds__(256) void k_gemm3(const bf16* __restrict__ AT,
                                               const bf16* __restrict__ SC,
                                               float* __restrict__ out0) {
    __shared__ alignas(16) bf16 As[128 * 64];
    __shared__ alignas(16) bf16 Bs[128 * 64];
    const int b  = blockIdx.z;
    const int i0 = blockIdx.y * 128;
    const int m0 = blockIdx.x * 128;
    const int t = threadIdx.x, lane = t & 63, wid = t >> 6;
    const int wr = (wid >> 1) * 64, wc = (wid & 1) * 64;
    const bf16* Ag = AT + (size_t)b * IDF * L + (size_t)i0 * L;
    const bf16* Bg = SC + (size_t)b * M * L + (size_t)m0 * L;
    const int brow_in = lane >> 3;
    const int bsrc = (((lane & 7) ^ brow_in) * 8);
    f32x4 acc[4][4] = {};
    for (int k0 = 0; k0 < L; k0 += 64) {
#pragma unroll
        for (int j = 0; j < 4; j++) {
            int q = wid * 4 + j;                 // 0..15, rows q*8..+7
            int row = q * 8 + brow_in;
            gl_lds16(&Ag[(size_t)row * L + k0 + bsrc], &As[q * 512]);
            gl_lds16(&Bg[(size_t)row * L + k0 + bsrc], &Bs[q * 512]);
        }
        __syncthreads();
#pragma unroll
        for (int kk = 0; kk < 2; kk++) {
            const int g = kk * 4 + (lane >> 4);
            bf16x8 af[4], bb[4];
#pragma unroll
            for (int f = 0; f < 4; f++) {
                int row = wr + f * 16 + (lane & 15);
                af[f] = *reinterpret_cast<const bf16x8*>(&As[row * 64 + ((g ^ (row & 7)) * 8)]);
            }
#pragma unroll
            for (int f = 0; f < 4; f++) {
                int row = wc + f * 16 + (lane & 15);
                bb[f] = *reinterpret_cast<const bf16x8*>(&Bs[row * 64 + ((g ^ (row & 7)) * 8)]);
            }
#pragma unroll
            for (int fm = 0; fm < 4; fm++)
#pragma unroll
                for (int fn = 0; fn < 4; fn++)
                    acc[fm][fn] = __builtin_amdgcn_mfma_f32_16x16x32_bf16(af[fm], bb[fn], acc[fm][fn], 0, 0, 0);
        }
        __syncthreads();
    }
    float* o = out0 + (size_t)b * IDF * M + (size_t)(i0 + wr) * M + m0 + wc;
#pragma unroll
    for (int fm = 0; fm < 4; fm++)
#pragma unroll
        for (int fn = 0; fn < 4; fn++) {
            int row = fm * 16 + ((lane >> 4) << 2);
            int col = fn * 16 + (lane & 15);
#pragma unroll
            for (int r = 0; r < 4; r++) o[(size_t)(row + r) * M + col] = acc[fm][fn][r];
        }
}

extern "C" void kernel_launch(void* const* d_in, const int* in_sizes, int n_in,
                              void* d_out, int out_size, void* d_ws, size_t ws_size,
                              hipStream_t stream) {
    const float* WC  = (const float*)d_in[0];   // [16,1024,4096]
    const float* ctx = (const float*)d_in[1];   // [16,256,256]
    const float* w2  = (const float*)d_in[2];   // [4096,256]
    float* out0 = (float*)d_out;                           // [16,1024,4096]
    float* out1 = out0 + (size_t)NB * IDF * M;             // [16,256,1024]

    bf16* SCp  = (bf16*)d_ws;                       // [16][4096][256]
    bf16* ATp  = SCp + (size_t)NB * M * L;          // [16][1024][256]
    bf16* W2B  = ATp + (size_t)NB * IDF * L;        // [4096][256]
    bf16* CTXT = W2B + (size_t)M * CDF;             // [16][256][256]
    // ST = sourceC^T [16][256][4096] bf16 (67MB) lives in out0's region:
    // written by k_gemm1, consumed by k_attn, then out0 overwritten by k_gemm3.
    bf16* STp  = (bf16*)d_out;

    k_prep_w2 <<<dim3(M * CDF / 1024), 256, 0, stream>>>(w2, W2B);
    k_prep_ctxT<<<dim3(L / 32, CDF / 32, NB), dim3(32, 8), 0, stream>>>(ctx, CTXT);
    k_gemm1  <<<dim3(L / 128, M / 128, NB), 256, 0, stream>>>(W2B, CTXT, SCp, STp);
    k_attn   <<<dim3(IDF / 64, NB), 512, 0, stream>>>(WC, STp, ATp, out1);
    k_gemm3  <<<dim3(M / 128, IDF / 128, NB), 256, 0, stream>>>(ATp, SCp, out0);
}